// Round 1
// baseline (253.575 us; speedup 1.0000x reference)
//
#include <hip/hip_runtime.h>

typedef _Float16 f16;
typedef _Float16 f16x4 __attribute__((ext_vector_type(4)));
typedef _Float16 f16x8 __attribute__((ext_vector_type(8)));
typedef float f32x4 __attribute__((ext_vector_type(4)));

#define MFMA(a, b, c) __builtin_amdgcn_mfma_f32_16x16x32_f16((a), (b), (c), 0, 0, 0)

typedef __attribute__((address_space(1))) const void gvoid;
typedef __attribute__((address_space(3))) void lvoid;

__device__ __forceinline__ void gload16(const void* g, void* l) {
    __builtin_amdgcn_global_load_lds((gvoid*)g, (lvoid*)l, 16, 0, 0);
}

// ---------------------------------------------------------------------------
// Kernel 1: cast f32 -> f16 for in_data (4M elems) and 4 weights (4x1M elems)
// ---------------------------------------------------------------------------
__global__ void cast_all(const float* __restrict__ x,
                         const float* __restrict__ w0, const float* __restrict__ w1,
                         const float* __restrict__ w2, const float* __restrict__ w3,
                         f16* __restrict__ xb, f16* __restrict__ wb) {
    const int NX = 4096 * 1024;
    int i = (blockIdx.x * 256 + threadIdx.x) * 4;
    if (i < NX) {
        float4 v = *(const float4*)(x + i);
        f16x4 o = {(f16)v.x, (f16)v.y, (f16)v.z, (f16)v.w};
        *(f16x4*)(xb + i) = o;
    } else {
        int j = i - NX;  // [0, 4M)
        const float* s = (j < (1 << 20)) ? w0 : (j < (2 << 20)) ? w1
                       : (j < (3 << 20)) ? w2 : w3;
        int loc = j & ((1 << 20) - 1);
        float4 v = *(const float4*)(s + loc);
        f16x4 o = {(f16)v.x, (f16)v.y, (f16)v.z, (f16)v.w};
        *(f16x4*)(wb + j) = o;
    }
}

// ---------------------------------------------------------------------------
// Kernel 2/5: GEMM C[m][n] = sum_k A[m][k]*B[n][k]   (x @ W.T form)
// M=4096, N=1024, K=1024 fixed. m97 structure: 128x128 tile, BK=64,
// 4 waves each 64x64 out (4x4 frags of 16x16x32), global_load_lds staging.
// ---------------------------------------------------------------------------
template <bool FINAL>
__global__ void gemm_bt(const f16* __restrict__ A, const f16* __restrict__ Bw,
                        f16* __restrict__ Cf, float* __restrict__ Co,
                        const float* __restrict__ bias) {
    __shared__ __align__(16) f16 As[128 * 64];
    __shared__ __align__(16) f16 Bs[128 * 64];
    const int tid = threadIdx.x;
    const int lane = tid & 63, wid = tid >> 6;
    const int lo = lane & 15, hi = lane >> 4;
    const int wr = wid >> 1, wc = wid & 1;
    const int m0 = blockIdx.x * 128, n0 = blockIdx.y * 128;
    const char* Ab = (const char*)A;
    const char* Bb = (const char*)(Bw + (size_t)blockIdx.z * (1024 * 1024));

    f32x4 acc[4][4];
#pragma unroll
    for (int i = 0; i < 4; ++i)
#pragma unroll
        for (int j = 0; j < 4; ++j) acc[i][j] = (f32x4){0.f, 0.f, 0.f, 0.f};

    for (int kt = 0; kt < 16; ++kt) {
        const int kb = kt * 128;  // byte offset along K (64 f16)
#pragma unroll
        for (int rr = 0; rr < 4; ++rr) {
            int o = rr * 4096 + tid * 16;
            int row = o >> 7, colB = o & 127;
            gload16(Ab + (size_t)(m0 + row) * 2048 + kb + colB, (char*)As + o);
            gload16(Bb + (size_t)(n0 + row) * 2048 + kb + colB, (char*)Bs + o);
        }
        __syncthreads();
#pragma unroll
        for (int kc = 0; kc < 2; ++kc) {
            f16x8 af[4], bf[4];
#pragma unroll
            for (int f = 0; f < 4; ++f)
                af[f] = *(const f16x8*)(As + (wr * 64 + f * 16 + lo) * 64 + kc * 32 + hi * 8);
#pragma unroll
            for (int f = 0; f < 4; ++f)
                bf[f] = *(const f16x8*)(Bs + (wc * 64 + f * 16 + lo) * 64 + kc * 32 + hi * 8);
#pragma unroll
            for (int i = 0; i < 4; ++i)
#pragma unroll
                for (int j = 0; j < 4; ++j) acc[i][j] = MFMA(af[i], bf[j], acc[i][j]);
        }
        __syncthreads();
    }

    const int mbase = m0 + wr * 64 + hi * 4;
    const int nbase = n0 + wc * 64 + lo;
    if (FINAL) {
#pragma unroll
        for (int j = 0; j < 4; ++j) {
            float bj = bias[nbase + j * 16];
#pragma unroll
            for (int i = 0; i < 4; ++i)
#pragma unroll
                for (int r = 0; r < 4; ++r)
                    Co[(size_t)(mbase + i * 16 + r) * 1024 + nbase + j * 16] =
                        acc[i][j][r] + bj;
        }
    } else {
        f16* Cz = Cf + (size_t)blockIdx.z * (4096 * 1024);
#pragma unroll
        for (int i = 0; i < 4; ++i)
#pragma unroll
            for (int j = 0; j < 4; ++j)
#pragma unroll
                for (int r = 0; r < 4; ++r)
                    Cz[(size_t)(mbase + i * 16 + r) * 1024 + nbase + j * 16] =
                        (f16)acc[i][j][r];
    }
}

// ---------------------------------------------------------------------------
// Kernel 3: V [b*2048+s][1024] -> VT [b*1024+n][2048]   (per-batch transpose)
// ---------------------------------------------------------------------------
__global__ void transpose_v(const f16* __restrict__ V, f16* __restrict__ VT) {
    __shared__ __align__(16) f16 t[64][68];
    const int s0 = blockIdx.x * 64, n0 = blockIdx.y * 64, b = blockIdx.z;
    const int tr = threadIdx.x >> 4, tc = threadIdx.x & 15;
#pragma unroll
    for (int it = 0; it < 4; ++it) {
        int s = tr + it * 16;
        f16x4 v = *(const f16x4*)(V + (size_t)(b * 2048 + s0 + s) * 1024 + n0 + tc * 4);
        *(f16x4*)&t[s][tc * 4] = v;
    }
    __syncthreads();
#pragma unroll
    for (int it = 0; it < 4; ++it) {
        int n = tr + it * 16;
        f16x4 ov = {t[tc * 4 + 0][n], t[tc * 4 + 1][n], t[tc * 4 + 2][n], t[tc * 4 + 3][n]};
        *(f16x4*)(VT + (size_t)(b * 1024 + n0 + n) * 2048 + s0 + tc * 4) = ov;
    }
}

// ---------------------------------------------------------------------------
// Kernel 4: causal flash attention.
// Grid (32 qtiles reversed, 32 bh). 4 waves x 16 q-rows = 64 q/block.
// KVBLK=64. K tile [kv][64] and VT tile [d][kv] staged with XOR swizzle.
// ---------------------------------------------------------------------------
__global__ void attn(const f16* __restrict__ Q, const f16* __restrict__ K,
                     const f16* __restrict__ VT, f16* __restrict__ CTX) {
    __shared__ __align__(16) f16 Kl[64 * 64];
    __shared__ __align__(16) f16 Vl[64 * 64];
    __shared__ __align__(16) f16 Pl[4 * 16 * 72];
    const int tid = threadIdx.x;
    const int lane = tid & 63, w = tid >> 6;
    const int lo = lane & 15, hi = lane >> 4;
    const int qt = 31 - blockIdx.x;  // heavy tiles first
    const int bh = blockIdx.y;
    const int b = bh >> 4, h = bh & 15;
    const int qw0 = qt * 64 + w * 16;

    // Q fragments (hoisted): A-frag rows q = lo, k = kc*32 + hi*8
    const f16* qrow = Q + (size_t)(b * 2048 + qw0 + lo) * 1024 + h * 64 + hi * 8;
    f16x8 qa0 = *(const f16x8*)(qrow);
    f16x8 qa1 = *(const f16x8*)(qrow + 32);

    f32x4 ctx[4];
#pragma unroll
    for (int d = 0; d < 4; ++d) ctx[d] = (f32x4){0.f, 0.f, 0.f, 0.f};
    float mrun[4], lrun[4];
#pragma unroll
    for (int r = 0; r < 4; ++r) { mrun[r] = -3e38f; lrun[r] = 0.f; }

    f16* Pw = Pl + w * 16 * 72;
    const int nsteps = qt + 1;
    const char* Kb = (const char*)K;
    const char* Vb = (const char*)VT;

    for (int t = 0; t < nsteps; ++t) {
        const int kv0 = t * 64;
        // stage K tile [64 kv][64 hd] and VT tile [64 d][64 kv], XOR-swizzled
#pragma unroll
        for (int rr = 0; rr < 2; ++rr) {
            int o = rr * 4096 + tid * 16;
            int row = o >> 7;
            int colB = (o & 127) ^ ((row & 7) << 4);
            gload16(Kb + (size_t)(b * 2048 + kv0 + row) * 2048 + h * 128 + colB,
                    (char*)Kl + o);
            gload16(Vb + (size_t)(b * 1024 + h * 64 + row) * 4096 + kv0 * 2 + colB,
                    (char*)Vl + o);
        }
        __syncthreads();

        // QK^T: S frags [16 q][16 kv] x 4 along kv
        f32x4 s[4];
#pragma unroll
        for (int fj = 0; fj < 4; ++fj) {
            f32x4 a = (f32x4){0.f, 0.f, 0.f, 0.f};
            int kv = fj * 16 + lo;
#pragma unroll
            for (int kc = 0; kc < 2; ++kc) {
                int cb = ((kc * 64 + hi * 16)) ^ ((kv & 7) << 4);
                f16x8 kf = *(const f16x8*)((const char*)Kl + kv * 128 + cb);
                a = MFMA(kc ? qa1 : qa0, kf, a);
            }
            s[fj] = a;
        }

        // online softmax per q-row r (row q = hi*4 + r, col kv = fj*16 + lo)
        const bool needmask = (kv0 + 63 > qw0);
        float p[4][4];
#pragma unroll
        for (int r = 0; r < 4; ++r) {
            const int qab = qw0 + hi * 4 + r;
            float sv[4];
            float mx = -3e38f;
#pragma unroll
            for (int fj = 0; fj < 4; ++fj) {
                float v = s[fj][r] * 0.125f;
                if (needmask && (kv0 + fj * 16 + lo > qab)) v = -3e38f;
                sv[fj] = v;
                mx = fmaxf(mx, v);
            }
            mx = fmaxf(mx, __shfl_xor(mx, 1));
            mx = fmaxf(mx, __shfl_xor(mx, 2));
            mx = fmaxf(mx, __shfl_xor(mx, 4));
            mx = fmaxf(mx, __shfl_xor(mx, 8));
            float mnew = fmaxf(mrun[r], mx);
            float corr = __expf(mrun[r] - mnew);
            mrun[r] = mnew;
            float rs = 0.f;
#pragma unroll
            for (int fj = 0; fj < 4; ++fj) {
                float pv = __expf(sv[fj] - mnew);
                p[fj][r] = pv;
                rs += pv;
            }
            rs += __shfl_xor(rs, 1);
            rs += __shfl_xor(rs, 2);
            rs += __shfl_xor(rs, 4);
            rs += __shfl_xor(rs, 8);
            lrun[r] = lrun[r] * corr + rs;
#pragma unroll
            for (int d = 0; d < 4; ++d) ctx[d][r] *= corr;
        }

        // P -> per-wave LDS [16 q][72 kv-padded]
#pragma unroll
        for (int fj = 0; fj < 4; ++fj)
#pragma unroll
            for (int r = 0; r < 4; ++r)
                Pw[(hi * 4 + r) * 72 + fj * 16 + lo] = (f16)p[fj][r];

        // PV: ctx[16 q][64 d] += P[16 q][64 kv] @ V[64 kv][64 d]
        f16x8 pa0 = *(const f16x8*)(Pw + lo * 72 + hi * 8);
        f16x8 pa1 = *(const f16x8*)(Pw + lo * 72 + 32 + hi * 8);
#pragma unroll
        for (int df = 0; df < 4; ++df) {
            int d = df * 16 + lo;
#pragma unroll
            for (int kc = 0; kc < 2; ++kc) {
                int cb = ((kc * 64 + hi * 16)) ^ ((d & 7) << 4);
                f16x8 vf = *(const f16x8*)((const char*)Vl + d * 128 + cb);
                ctx[df] = MFMA(kc ? pa1 : pa0, vf, ctx[df]);
            }
        }
        __syncthreads();
    }

    // epilogue: normalize by l, store fp16 ctx
#pragma unroll
    for (int df = 0; df < 4; ++df)
#pragma unroll
        for (int r = 0; r < 4; ++r) {
            float val = ctx[df][r] / lrun[r];
            CTX[(size_t)(b * 2048 + qw0 + hi * 4 + r) * 1024 + h * 64 + df * 16 + lo] =
                (f16)val;
        }
}

// ---------------------------------------------------------------------------
extern "C" void kernel_launch(void* const* d_in, const int* in_sizes, int n_in,
                              void* d_out, int out_size, void* d_ws, size_t ws_size,
                              hipStream_t stream) {
    const float* x = (const float*)d_in[0];
    const float* wq = (const float*)d_in[1];
    const float* wk = (const float*)d_in[2];
    const float* wv = (const float*)d_in[3];
    const float* wo = (const float*)d_in[4];
    const float* bo = (const float*)d_in[5];

    const size_t M1 = 1024 * 1024;
    f16* Xb = (f16*)d_ws;          // 4M f16 (8 MB); later reused as VT
    f16* Wh = Xb + 4 * M1;         // 4M f16: Wq|Wk|Wv|Wo
    f16* QKV = Wh + 4 * M1;        // 12M f16
    f16* Q = QKV;
    f16* K = QKV + 4 * M1;
    f16* V = QKV + 8 * M1;
    f16* VT = Xb;                  // alias: Xb dead after QKV GEMM
    f16* CTX = V;                  // alias: V dead after transpose
    float* out = (float*)d_out;

    cast_all<<<dim3(8192), dim3(256), 0, stream>>>(x, wq, wk, wv, wo, Xb, Wh);
    gemm_bt<false><<<dim3(32, 8, 3), dim3(256), 0, stream>>>(Xb, Wh, QKV, nullptr, nullptr);
    transpose_v<<<dim3(32, 16, 2), dim3(256), 0, stream>>>(V, VT);
    attn<<<dim3(32, 32), dim3(256), 0, stream>>>(Q, K, VT, CTX);
    gemm_bt<true><<<dim3(32, 8, 1), dim3(256), 0, stream>>>(CTX, Wh + 3 * M1, nullptr, out, bo);
}

// Round 4
// 185.548 us; speedup vs baseline: 1.3666x; 1.3666x over previous
//
#include <hip/hip_runtime.h>

typedef _Float16 f16;
typedef _Float16 f16x4 __attribute__((ext_vector_type(4)));
typedef _Float16 f16x8 __attribute__((ext_vector_type(8)));
typedef float f32x4 __attribute__((ext_vector_type(4)));

#define MFMA(a, b, c) __builtin_amdgcn_mfma_f32_16x16x32_f16((a), (b), (c), 0, 0, 0)

typedef __attribute__((address_space(1))) const void gvoid;
typedef __attribute__((address_space(3))) void lvoid;

__device__ __forceinline__ void gload16(const void* g, void* l) {
    __builtin_amdgcn_global_load_lds((gvoid*)g, (lvoid*)l, 16, 0, 0);
}

// ---------------------------------------------------------------------------
// Kernel 1: cast f32 -> f16 for in_data (4M elems) and 4 weights (4x1M elems)
// ---------------------------------------------------------------------------
__global__ void cast_all(const float* __restrict__ x,
                         const float* __restrict__ w0, const float* __restrict__ w1,
                         const float* __restrict__ w2, const float* __restrict__ w3,
                         f16* __restrict__ xb, f16* __restrict__ wb) {
    const int NX = 4096 * 1024;
    int i = (blockIdx.x * 256 + threadIdx.x) * 4;
    if (i < NX) {
        float4 v = *(const float4*)(x + i);
        f16x4 o = {(f16)v.x, (f16)v.y, (f16)v.z, (f16)v.w};
        *(f16x4*)(xb + i) = o;
    } else {
        int j = i - NX;  // [0, 4M)
        const float* s = (j < (1 << 20)) ? w0 : (j < (2 << 20)) ? w1
                       : (j < (3 << 20)) ? w2 : w3;
        int loc = j & ((1 << 20) - 1);
        float4 v = *(const float4*)(s + loc);
        f16x4 o = {(f16)v.x, (f16)v.y, (f16)v.z, (f16)v.w};
        *(f16x4*)(wb + j) = o;
    }
}

// ---------------------------------------------------------------------------
// Kernel 2/4: GEMM C[m][n] = sum_k A[m][k]*B[n][k]   (x @ W.T form)
// M=4096, N=1024, K=1024. 128x128 tile, BK=64, 4 waves, global_load_lds.
// !FINAL: z=0 -> Q (scaled by 0.125), z=1 -> K, z=2 -> V written TRANSPOSED
// into VT[b*1024 + n][2048 s].
// ---------------------------------------------------------------------------
template <bool FINAL>
__global__ void gemm_bt(const f16* __restrict__ A, const f16* __restrict__ Bw,
                        f16* __restrict__ Cf, f16* __restrict__ VTo,
                        float* __restrict__ Co, const float* __restrict__ bias) {
    __shared__ __align__(16) f16 As[128 * 64];
    __shared__ __align__(16) f16 Bs[128 * 64];
    const int tid = threadIdx.x;
    const int lane = tid & 63, wid = tid >> 6;
    const int lo = lane & 15, hi = lane >> 4;
    const int wr = wid >> 1, wc = wid & 1;
    const int m0 = blockIdx.x * 128, n0 = blockIdx.y * 128;
    const char* Ab = (const char*)A;
    const char* Bb = (const char*)(Bw + (size_t)blockIdx.z * (1024 * 1024));

    f32x4 acc[4][4];
#pragma unroll
    for (int i = 0; i < 4; ++i)
#pragma unroll
        for (int j = 0; j < 4; ++j) acc[i][j] = (f32x4){0.f, 0.f, 0.f, 0.f};

    for (int kt = 0; kt < 16; ++kt) {
        const int kb = kt * 128;  // byte offset along K (64 f16)
#pragma unroll
        for (int rr = 0; rr < 4; ++rr) {
            int o = rr * 4096 + tid * 16;
            int row = o >> 7, colB = o & 127;
            gload16(Ab + (size_t)(m0 + row) * 2048 + kb + colB, (char*)As + o);
            gload16(Bb + (size_t)(n0 + row) * 2048 + kb + colB, (char*)Bs + o);
        }
        __syncthreads();
#pragma unroll
        for (int kc = 0; kc < 2; ++kc) {
            f16x8 af[4], bf[4];
#pragma unroll
            for (int f = 0; f < 4; ++f)
                af[f] = *(const f16x8*)(As + (wr * 64 + f * 16 + lo) * 64 + kc * 32 + hi * 8);
#pragma unroll
            for (int f = 0; f < 4; ++f)
                bf[f] = *(const f16x8*)(Bs + (wc * 64 + f * 16 + lo) * 64 + kc * 32 + hi * 8);
#pragma unroll
            for (int i = 0; i < 4; ++i)
#pragma unroll
                for (int j = 0; j < 4; ++j) acc[i][j] = MFMA(af[i], bf[j], acc[i][j]);
        }
        __syncthreads();
    }

    const int mbase = m0 + wr * 64 + hi * 4;
    const int nbase = n0 + wc * 64 + lo;
    if (FINAL) {
#pragma unroll
        for (int j = 0; j < 4; ++j) {
            float bj = bias[nbase + j * 16];
#pragma unroll
            for (int i = 0; i < 4; ++i)
#pragma unroll
                for (int r = 0; r < 4; ++r)
                    Co[(size_t)(mbase + i * 16 + r) * 1024 + nbase + j * 16] =
                        acc[i][j][r] + bj;
        }
    } else if (blockIdx.z == 2) {
        // V written transposed: VT[(b*1024 + n)][s],  m = b*2048+s
#pragma unroll
        for (int i = 0; i < 4; ++i)
#pragma unroll
            for (int j = 0; j < 4; ++j)
#pragma unroll
                for (int r = 0; r < 4; ++r) {
                    int m = mbase + i * 16 + r, n = nbase + j * 16;
                    VTo[(size_t)((m >> 11) * 1024 + n) * 2048 + (m & 2047)] =
                        (f16)acc[i][j][r];
                }
    } else {
        const float osc = (blockIdx.z == 0) ? 0.125f : 1.0f;  // fold 1/sqrt(64) into Q
        f16* Cz = Cf + (size_t)blockIdx.z * (4096 * 1024);
#pragma unroll
        for (int i = 0; i < 4; ++i)
#pragma unroll
            for (int j = 0; j < 4; ++j)
#pragma unroll
                for (int r = 0; r < 4; ++r)
                    Cz[(size_t)(mbase + i * 16 + r) * 1024 + nbase + j * 16] =
                        (f16)(acc[i][j][r] * osc);
    }
}

// ---------------------------------------------------------------------------
// Kernel 3: causal flash attention, swapped-QK^T lane-local softmax.
// Double-buffered K/V in statically-distinct LDS arrays; sync structure is
// { __syncthreads(); issue stage(t+1); compute(t) } — loads for t+1 fly under
// compute t and are drained by the NEXT iteration's __syncthreads (full
// fence+drain; race-free, proven in round 0).
// Grid (32 bh, 32 qt reversed) -> XCD = bh%8. 4 waves x 16 q-rows, KVBLK=64.
// ---------------------------------------------------------------------------
__global__ __launch_bounds__(256) void attn(const f16* __restrict__ Q,
                                            const f16* __restrict__ K,
                                            const f16* __restrict__ VT,
                                            f16* __restrict__ CTX) {
    __shared__ __align__(16) f16 K0[64 * 64];
    __shared__ __align__(16) f16 K1[64 * 64];
    __shared__ __align__(16) f16 V0[64 * 64];
    __shared__ __align__(16) f16 V1[64 * 64];
    __shared__ __align__(16) f16 Pl[4 * 16 * 72];
    const int tid = threadIdx.x;
    const int lane = tid & 63, w = tid >> 6;
    const int lo = lane & 15, hi = lane >> 4;
    const int bh = blockIdx.x;
    const int qt = 31 - blockIdx.y;  // heavy tiles dispatch first
    const int b = bh >> 4, h = bh & 15;
    const int qw0 = qt * 64 + w * 16;
    const int qglob = qw0 + lo;

    // Q fragments (B-operand of swapped QK^T): col=q=lo, k=kc*32+hi*8+j
    const f16* qrow = Q + (size_t)(b * 2048 + qw0 + lo) * 1024 + h * 64 + hi * 8;
    const f16x8 qa0 = *(const f16x8*)(qrow);
    const f16x8 qa1 = *(const f16x8*)(qrow + 32);

    f32x4 ctx[4];
#pragma unroll
    for (int d = 0; d < 4; ++d) ctx[d] = (f32x4){0.f, 0.f, 0.f, 0.f};
    float mrun = -3e38f, lrun = 0.f;

    f16* Pw = Pl + w * (16 * 72);
    const char* Kb = (const char*)K;
    const char* Vb = (const char*)VT;

    auto stage = [&](f16* Kd, f16* Vd, int t) {
        const int kv0 = t * 64;
#pragma unroll
        for (int rr = 0; rr < 2; ++rr) {
            int o = rr * 4096 + tid * 16;
            int row = o >> 7;
            int colB = (o & 127) ^ ((row & 7) << 4);
            gload16(Kb + (size_t)(b * 2048 + kv0 + row) * 2048 + h * 128 + colB,
                    (char*)Kd + o);
            gload16(Vb + (size_t)(b * 1024 + h * 64 + row) * 4096 + (size_t)kv0 * 2 + colB,
                    (char*)Vd + o);
        }
    };

    auto compute = [&](const f16* Klb, const f16* Vlb, int t) {
        // QK^T swapped: S^T frag, lane owns q=qw0+lo, kv=fj*16+hi*4+r
        f32x4 s4[4];
        __builtin_amdgcn_s_setprio(1);
#pragma unroll
        for (int fj = 0; fj < 4; ++fj) {
            f32x4 a = (f32x4){0.f, 0.f, 0.f, 0.f};
            const int kv = fj * 16 + lo;  // A-frag row
#pragma unroll
            for (int kc = 0; kc < 2; ++kc) {
                const int cb = (kc * 64 + hi * 16) ^ ((kv & 7) << 4);
                f16x8 kf = *(const f16x8*)((const char*)Klb + kv * 128 + cb);
                a = MFMA(kf, kc ? qa1 : qa0, a);
            }
            s4[fj] = a;
        }
        __builtin_amdgcn_s_setprio(0);

        // lane-local softmax over 16 kv values (+2 shfls across hi-groups)
        float pv[16];
        if (t == qt) {  // wave-uniform: only the diagonal tile masks
#pragma unroll
            for (int fj = 0; fj < 4; ++fj)
#pragma unroll
                for (int r = 0; r < 4; ++r) {
                    const int kvg = t * 64 + fj * 16 + hi * 4 + r;
                    pv[fj * 4 + r] = (kvg > qglob) ? -3e38f : s4[fj][r];
                }
        } else {
#pragma unroll
            for (int fj = 0; fj < 4; ++fj)
#pragma unroll
                for (int r = 0; r < 4; ++r) pv[fj * 4 + r] = s4[fj][r];
        }

        float tm[8];
#pragma unroll
        for (int i = 0; i < 8; ++i) tm[i] = fmaxf(pv[i], pv[i + 8]);
#pragma unroll
        for (int i = 0; i < 4; ++i) tm[i] = fmaxf(tm[i], tm[i + 4]);
        float mx = fmaxf(fmaxf(tm[0], tm[1]), fmaxf(tm[2], tm[3]));
        mx = fmaxf(mx, __shfl_xor(mx, 16));
        mx = fmaxf(mx, __shfl_xor(mx, 32));

        const float mnew = fmaxf(mrun, mx);
        const float corr = __expf(mrun - mnew);
        mrun = mnew;
#pragma unroll
        for (int i = 0; i < 16; ++i) pv[i] = __expf(pv[i] - mnew);
        float ts[8];
#pragma unroll
        for (int i = 0; i < 8; ++i) ts[i] = pv[i] + pv[i + 8];
#pragma unroll
        for (int i = 0; i < 4; ++i) ts[i] = ts[i] + ts[i + 4];
        float rs = (ts[0] + ts[1]) + (ts[2] + ts[3]);
        rs += __shfl_xor(rs, 16);
        rs += __shfl_xor(rs, 32);
        lrun = lrun * corr + rs;

        // rescale ctx rows (ctx row q' = hi*4+r; corr lives on lane lo=q')
#pragma unroll
        for (int r = 0; r < 4; ++r) {
            const float cq = __shfl(corr, hi * 4 + r);
            ctx[0][r] *= cq; ctx[1][r] *= cq; ctx[2][r] *= cq; ctx[3][r] *= cq;
        }

        // P -> per-wave LDS (vectorized f16x4: kv consecutive in r)
#pragma unroll
        for (int fj = 0; fj < 4; ++fj) {
            f16x4 w4 = {(f16)pv[fj * 4 + 0], (f16)pv[fj * 4 + 1],
                        (f16)pv[fj * 4 + 2], (f16)pv[fj * 4 + 3]};
            *(f16x4*)(Pw + lo * 72 + fj * 16 + hi * 4) = w4;
        }
        const f16x8 pa0 = *(const f16x8*)(Pw + lo * 72 + hi * 8);
        const f16x8 pa1 = *(const f16x8*)(Pw + lo * 72 + 32 + hi * 8);

        __builtin_amdgcn_s_setprio(1);
#pragma unroll
        for (int df = 0; df < 4; ++df) {
            const int d = df * 16 + lo;
#pragma unroll
            for (int kc = 0; kc < 2; ++kc) {
                const int cb = (kc * 64 + hi * 16) ^ ((d & 7) << 4);
                f16x8 vf = *(const f16x8*)((const char*)Vlb + d * 128 + cb);
                ctx[df] = MFMA(kc ? pa1 : pa0, vf, ctx[df]);
            }
        }
        __builtin_amdgcn_s_setprio(0);
    };

    stage(&K0[0], &V0[0], 0);
    for (int t = 0; t <= qt; ++t) {
        __syncthreads();  // drains stage(t) loads (all waves) + full fence
        if ((t & 1) == 0) {
            if (t < qt) stage(&K1[0], &V1[0], t + 1);
            compute(&K0[0], &V0[0], t);
        } else {
            if (t < qt) stage(&K0[0], &V0[0], t + 1);
            compute(&K1[0], &V1[0], t);
        }
    }

    // epilogue: ctx row q'=hi*4+r, col d=df*16+lo; lrun lives on lane lo=q'
#pragma unroll
    for (int r = 0; r < 4; ++r) {
        const float lq = __shfl(lrun, hi * 4 + r);
        const float inv = 1.0f / lq;
#pragma unroll
        for (int df = 0; df < 4; ++df)
            CTX[(size_t)(b * 2048 + qw0 + hi * 4 + r) * 1024 + h * 64 + df * 16 + lo] =
                (f16)(ctx[df][r] * inv);
    }
}

// ---------------------------------------------------------------------------
extern "C" void kernel_launch(void* const* d_in, const int* in_sizes, int n_in,
                              void* d_out, int out_size, void* d_ws, size_t ws_size,
                              hipStream_t stream) {
    const float* x = (const float*)d_in[0];
    const float* wq = (const float*)d_in[1];
    const float* wk = (const float*)d_in[2];
    const float* wv = (const float*)d_in[3];
    const float* wo = (const float*)d_in[4];
    const float* bo = (const float*)d_in[5];

    const size_t M1 = 1024 * 1024;
    f16* VT = (f16*)d_ws;          // 4M f16 (8 MB): V transposed [b*1024+n][2048]
    f16* Wh = VT + 4 * M1;         // 4M f16: Wq|Wk|Wv|Wo
    f16* QKV = Wh + 4 * M1;        // Q (4M) | K (4M)
    f16* Xb = QKV + 8 * M1;        // x cast; region later reused as CTX
    f16* Q = QKV;
    f16* K = QKV + 4 * M1;
    f16* CTX = QKV + 8 * M1;       // alias Xb: x dead after QKV GEMM
    float* out = (float*)d_out;

    cast_all<<<dim3(8192), dim3(256), 0, stream>>>(x, wq, wk, wv, wo, Xb, Wh);
    gemm_bt<false><<<dim3(32, 8, 3), dim3(256), 0, stream>>>(Xb, Wh, QKV, VT, nullptr, nullptr);
    attn<<<dim3(32, 32), dim3(256), 0, stream>>>(Q, K, VT, CTX);
    gemm_bt<true><<<dim3(32, 8, 1), dim3(256), 0, stream>>>(CTX, Wh + 3 * M1, nullptr, nullptr, out, bo);
}